// Round 9
// baseline (961.304 us; speedup 1.0000x reference)
//
#include <hip/hip_runtime.h>
#include <stdint.h>

#define BB 16
#define NN 4096
#define CC 64
#define NPOINT 1024
#define KK 32
#define F1 64
#define F2 64
#define F3 128

#define BLK_T 512          // uniform block size
#define FPS_ACT 256        // active FPS lanes (4 waves)
#define FPPT 16            // points per FPS lane = 8 v2f pairs

typedef float v2f __attribute__((ext_vector_type(2)));

// ---------------- DPP 64-lane max-reduce helpers ----------------
#if defined(__has_builtin)
#if __has_builtin(__builtin_amdgcn_update_dpp)
#define HAS_DPP 1
#endif
#endif

#ifdef HAS_DPP
template <int CTRL>
__device__ __forceinline__ unsigned long long dpp_move64(unsigned long long k) {
    int lo = __builtin_amdgcn_update_dpp(0, (int)(unsigned)k,         CTRL, 0xF, 0xF, false);
    int hi = __builtin_amdgcn_update_dpp(0, (int)(unsigned)(k >> 32), CTRL, 0xF, 0xF, false);
    return ((unsigned long long)(unsigned)hi << 32) | (unsigned)lo;
}
__device__ __forceinline__ unsigned long long wave_max_key(unsigned long long key) {
    unsigned long long o;
    o = dpp_move64<0x111>(key); if (o > key) key = o;   // row_shr:1
    o = dpp_move64<0x112>(key); if (o > key) key = o;   // row_shr:2
    o = dpp_move64<0x114>(key); if (o > key) key = o;   // row_shr:4
    o = dpp_move64<0x118>(key); if (o > key) key = o;   // row_shr:8
    o = dpp_move64<0x142>(key); if (o > key) key = o;   // row_bcast15
    o = dpp_move64<0x143>(key); if (o > key) key = o;   // row_bcast31 -> lane63 has max
    return key;
}
#else
__device__ __forceinline__ unsigned long long wave_max_key(unsigned long long key) {
#pragma unroll
    for (int off = 32; off > 0; off >>= 1) {
        unsigned long long o = __shfl_xor(key, off, 64);
        if (o > key) key = o;
    }
    return key;
}
#endif

// shared-memory arena (union of FPS and MLP layouts)
// FPS : xs[4096] ys[4096] zs[4096] @0 (49152) | wred 2x4 u64 @49152 | cbuf 96f @49280
// MLP : gbuf 64x68 @0 (17408) | hbuf 64x64 @17408 (16384) | pmax 16x128 @33792 (8192)
//       cmask 2x64 u64 @41984 (1024) | nbr 2x32 int @43008 (256)  -> 43264
#define SMEM_BYTES 49664   // 3 blocks/CU

__global__ __launch_bounds__(BLK_T)
void fused_kernel(const float* __restrict__ xyz,
                  const float* __restrict__ points,
                  const float* __restrict__ w0, const float* __restrict__ b0,
                  const float* __restrict__ w1, const float* __restrict__ b1,
                  const float* __restrict__ w2, const float* __restrict__ b2,
                  float* __restrict__ out_xyz,
                  float* __restrict__ out_points,
                  int* __restrict__ ctr) {
    __shared__ __align__(16) char smem[SMEM_BYTES];
    const int tid = threadIdx.x;

    if (blockIdx.x < BB) {
        // ================= FPS (blocks 0..15, resident first => no deadlock) ====
        asm volatile("s_setprio 3");
        const int wid8 = tid >> 6;
        if (wid8 >= 4) {
            // barrier-only companion waves: exactly 1 + NPOINT barriers
            for (int i = 0; i < NPOINT + 1; ++i) __syncthreads();
            return;
        }
        float* xs = (float*)smem;
        float* ys = xs + NN;
        float* zs = ys + NN;
        unsigned long long (*wred)[4] =
            (unsigned long long (*)[4])(smem + 49152);
        float* cbuf = (float*)(smem + 49280);   // 32 centroids staging

        const int b = blockIdx.x;
        const int lane = tid & 63, wv = tid >> 6;   // wv 0..3
        const float* __restrict__ xb = xyz + (size_t)b * (NN * 3);

        // pair j holds points p = tid + (2j+h)*256, h = 0/1
        v2f px2[8], py2[8], pz2[8], dd[8];
#pragma unroll
        for (int j = 0; j < 8; ++j) {
#pragma unroll
            for (int h = 0; h < 2; ++h) {
                int p = tid + (2 * j + h) * FPS_ACT;
                float x = xb[p * 3 + 0];
                float y = xb[p * 3 + 1];
                float z = xb[p * 3 + 2];
                px2[j][h] = x; py2[j][h] = y; pz2[j][h] = z;
                xs[p] = x; ys[p] = y; zs[p] = z;
            }
            dd[j] = (v2f){1e10f, 1e10f};
        }
        __syncthreads();

        float cx = xs[0], cy = ys[0], cz = zs[0];
        float* xo = out_xyz + (size_t)b * NPOINT * 3;

        for (int i = 0; i < NPOINT; ++i) {
            if (tid == 0) {
                cbuf[(i & 31) * 3 + 0] = cx;
                cbuf[(i & 31) * 3 + 1] = cy;
                cbuf[(i & 31) * 3 + 2] = cz;
            }
            // ---- packed dist update: v_pk rn-exact, no FMA contraction ----
            {
#pragma clang fp contract(off)
                v2f c2x = (v2f){cx, cx}, c2y = (v2f){cy, cy}, c2z = (v2f){cz, cz};
#pragma unroll
                for (int j = 0; j < 8; ++j) {
                    v2f dx = px2[j] - c2x;
                    v2f dy = py2[j] - c2y;
                    v2f dz = pz2[j] - c2z;
                    v2f ss = (dx * dx + dy * dy) + dz * dz;  // ((x2+y2)+z2), each rn
                    dd[j] = __builtin_elementwise_min(dd[j], ss);
                }
            }
            // ---- lane-local argmax: packed max tree + first-occurrence scan ----
            v2f m0 = __builtin_elementwise_max(dd[0], dd[1]);
            v2f m1 = __builtin_elementwise_max(dd[2], dd[3]);
            v2f m2 = __builtin_elementwise_max(dd[4], dd[5]);
            v2f m3 = __builtin_elementwise_max(dd[6], dd[7]);
            m0 = __builtin_elementwise_max(m0, m1);
            m2 = __builtin_elementwise_max(m2, m3);
            m0 = __builtin_elementwise_max(m0, m2);
            float bd = fmaxf(m0.x, m0.y);
            int bp = 0;
#pragma unroll
            for (int j = 7; j >= 0; --j) {      // descending => smallest p wins
                if (dd[j].y == bd) bp = tid + (2 * j + 1) * FPS_ACT;
                if (dd[j].x == bd) bp = tid + (2 * j + 0) * FPS_ACT;
            }
            unsigned long long key = (((unsigned long long)__float_as_uint(bd)) << 32)
                                   | (unsigned int)(NN - 1 - bp);
            key = wave_max_key(key);
            if (lane == 63) wred[i & 1][wv] = key;
            __syncthreads();

            unsigned long long best = wred[i & 1][0];
#pragma unroll
            for (int w = 1; w < 4; ++w) {
                unsigned long long o = wred[i & 1][w];
                if (o > best) best = o;
            }
            int bi = (NN - 1) - (int)(best & 0xffffffffu);

            // publish 32 centroids every 32 iters
            if (tid == 0 && (i & 31) == 31) {
                const float4* src = (const float4*)cbuf;
                float4* dst = (float4*)(xo + (size_t)(i - 31) * 3);
#pragma unroll
                for (int q = 0; q < 24; ++q) dst[q] = src[q];
                __hip_atomic_store(&ctr[b * 16], i + 1,
                                   __ATOMIC_RELEASE, __HIP_MEMORY_SCOPE_AGENT);
            }
            cx = xs[bi]; cy = ys[bi]; cz = zs[bi];
        }
    } else {
        // ======== fused ball query + gather + MLP + maxpool, 2 groups/block ====
        float (*gbuf)[68] = (float (*)[68])smem;                 // 64 rows
        float (*hbuf)[F1] = (float (*)[F1])(smem + 17408);       // 64 rows
        float (*pmax)[F3] = (float (*)[F3])(smem + 33792);       // 16 rows
        unsigned long long* cmask = (unsigned long long*)(smem + 41984);  // [2][64]
        int* nbr = (int*)(smem + 43008);                          // [2][32]

        const int gi = blockIdx.x - BB;
        const int sp = gi >> 4;         // s-pair, s-major for progressive consume
        const int b = gi & 15;
        const int s0 = sp * 2;
        const int g0 = b * NPOINT + s0;
        const int f = tid & 63;
        const int wid = tid >> 6;       // 0..7

        // wait until centroid s0+1 is published; adaptive backoff (poison<0 => long)
        if (tid == 0) {
            const int target = s0 + 2;
            int c;
            while ((c = __hip_atomic_load(&ctr[b * 16], __ATOMIC_RELAXED,
                                          __HIP_MEMORY_SCOPE_AGENT)) < target) {
                if (target - c > 64) __builtin_amdgcn_s_sleep(64);
                else                 __builtin_amdgcn_s_sleep(4);
            }
            (void)__hip_atomic_load(&ctr[b * 16], __ATOMIC_ACQUIRE,
                                    __HIP_MEMORY_SCOPE_AGENT);
        }
        __syncthreads();

        // centroids via agent-scope loads (LLC-direct, stale-L2-immune)
        float cen[2][3];
#pragma unroll
        for (int grp = 0; grp < 2; ++grp)
#pragma unroll
            for (int q = 0; q < 3; ++q) {
                unsigned int u = __hip_atomic_load(
                    (unsigned int*)&out_xyz[(size_t)(g0 + grp) * 3 + q],
                    __ATOMIC_RELAXED, __HIP_MEMORY_SCOPE_AGENT);
                cen[grp][q] = __uint_as_float(u);
            }
        const float cx0 = cen[0][0], cy0 = cen[0][1], cz0 = cen[0][2];
        const float cx1 = cen[1][0], cy1 = cen[1][1], cz1 = cen[1][2];

        // ---- phase A1: 8 waves scan all 4096 points, 2 centroids at once ----
        {
            const float* __restrict__ xb = xyz + (size_t)b * (NN * 3);
#pragma unroll
            for (int j = 0; j < 8; ++j) {
                int chunk = wid * 8 + j;
                int p = chunk * 64 + f;
                float x = xb[p * 3 + 0];
                float y = xb[p * 3 + 1];
                float z = xb[p * 3 + 2];
                float dx0 = __fsub_rn(cx0, x), dy0 = __fsub_rn(cy0, y), dz0 = __fsub_rn(cz0, z);
                float d20 = __fadd_rn(__fadd_rn(__fmul_rn(dx0, dx0), __fmul_rn(dy0, dy0)),
                                      __fmul_rn(dz0, dz0));
                float dx1 = __fsub_rn(cx1, x), dy1 = __fsub_rn(cy1, y), dz1 = __fsub_rn(cz1, z);
                float d21 = __fadd_rn(__fadd_rn(__fmul_rn(dx1, dx1), __fmul_rn(dy1, dy1)),
                                      __fmul_rn(dz1, dz1));
                unsigned long long m0 = __ballot(d20 <= 0.04f);
                unsigned long long m1 = __ballot(d21 <= 0.04f);
                if (f == 0) { cmask[chunk] = m0; cmask[64 + chunk] = m1; }
            }
        }
        __syncthreads();

        // ---- phase A2: waves 0,1 — ordered compaction per group ----
        if (tid < 128) {
            const int grp = wid;
            unsigned long long m = cmask[grp * 64 + f];
            int cnt = (int)__popcll(m);
            int v = cnt;
#pragma unroll
            for (int off = 1; off < 64; off <<= 1) {
                int u = __shfl_up(v, off, 64);
                if (f >= off) v += u;
            }
            int excl = v - cnt;
            int total = __shfl(v, 63, 64);
            unsigned long long mm = m;
            int r = excl;
            while (mm && r < KK) {
                int bpos = __ffsll(mm) - 1;
                mm &= mm - 1;
                nbr[grp * 32 + (r++)] = f * 64 + bpos;
            }
            if (total < KK) {
                unsigned long long nz = __ballot(cnt > 0);
                int fchunk = __ffsll(nz) - 1;
                unsigned long long fm = cmask[grp * 64 + fchunk];
                int first = fchunk * 64 + __ffsll(fm) - 1;
                if (f >= total && f < KK) nbr[grp * 32 + f] = first;
            }
        }
        __syncthreads();

        // ---- phase B: gather both groups into LDS (rows 0..31 g0, 32..63 g1) ----
        {
            const float* __restrict__ pb = points + (size_t)b * NN * CC;
#pragma unroll
            for (int m = 0; m < 8; ++m) {
                int r = wid + 8 * m;           // 0..63
                int grp = r >> 5, k = r & 31;
                int idx = nbr[grp * 32 + k] & (NN - 1);
                gbuf[r][f] = pb[(size_t)idx * CC + f];
            }
            if (tid < 192) {
                int r = tid & 63, q = tid >> 6;
                int grp = r >> 5, k = r & 31;
                int idx = nbr[grp * 32 + k] & (NN - 1);
                float v = xyz[((size_t)b * NN + idx) * 3 + q];
                gbuf[r][CC + q] = __fsub_rn(v, cen[grp][q]);
            }
        }
        __syncthreads();

        v2f acc2[8];

        // ---- layer 1: 67 -> 64 ----
#pragma unroll
        for (int m = 0; m < 8; ++m) acc2[m] = (v2f){0.0f, 0.0f};
#pragma unroll 4
        for (int c4 = 0; c4 < 64; c4 += 4) {
            v2f wA = (v2f){w0[(c4 + 0) * F1 + f], w0[(c4 + 1) * F1 + f]};
            v2f wB = (v2f){w0[(c4 + 2) * F1 + f], w0[(c4 + 3) * F1 + f]};
#pragma unroll
            for (int m = 0; m < 8; ++m) {
                float4 gv = *(const float4*)&gbuf[wid + 8 * m][c4];
                acc2[m] = __builtin_elementwise_fma((v2f){gv.x, gv.y}, wA, acc2[m]);
                acc2[m] = __builtin_elementwise_fma((v2f){gv.z, gv.w}, wB, acc2[m]);
            }
        }
        {
            float wv0 = w0[64 * F1 + f];
            float wv1 = w0[65 * F1 + f];
            float wv2 = w0[66 * F1 + f];
            float bb = b0[f];
#pragma unroll
            for (int m = 0; m < 8; ++m) {
                int r = wid + 8 * m;
                float a = acc2[m].x + acc2[m].y;
                a = fmaf(gbuf[r][64], wv0, a);
                a = fmaf(gbuf[r][65], wv1, a);
                a = fmaf(gbuf[r][66], wv2, a);
                hbuf[r][f] = fmaxf(a + bb, 0.0f);
            }
        }
        __syncthreads();

        // ---- layer 2: 64 -> 64 ----
#pragma unroll
        for (int m = 0; m < 8; ++m) acc2[m] = (v2f){0.0f, 0.0f};
#pragma unroll 4
        for (int c4 = 0; c4 < 64; c4 += 4) {
            v2f wA = (v2f){w1[(c4 + 0) * F2 + f], w1[(c4 + 1) * F2 + f]};
            v2f wB = (v2f){w1[(c4 + 2) * F2 + f], w1[(c4 + 3) * F2 + f]};
#pragma unroll
            for (int m = 0; m < 8; ++m) {
                float4 gv = *(const float4*)&hbuf[wid + 8 * m][c4];
                acc2[m] = __builtin_elementwise_fma((v2f){gv.x, gv.y}, wA, acc2[m]);
                acc2[m] = __builtin_elementwise_fma((v2f){gv.z, gv.w}, wB, acc2[m]);
            }
        }
        {
            float bb = b1[f];
#pragma unroll
            for (int m = 0; m < 8; ++m)
                gbuf[wid + 8 * m][f] = fmaxf(acc2[m].x + acc2[m].y + bb, 0.0f);
        }
        __syncthreads();

        // ---- layer 3: 64 -> 128 in two output-column halves + maxpool ----
        // rows m 0..3 -> group0 ; m 4..7 -> group1
#pragma unroll
        for (int h = 0; h < 2; ++h) {
#pragma unroll
            for (int m = 0; m < 8; ++m) acc2[m] = (v2f){0.0f, 0.0f};
#pragma unroll 4
            for (int c4 = 0; c4 < 64; c4 += 4) {
                v2f wA = (v2f){w2[(c4 + 0) * F3 + 64 * h + f], w2[(c4 + 1) * F3 + 64 * h + f]};
                v2f wB = (v2f){w2[(c4 + 2) * F3 + 64 * h + f], w2[(c4 + 3) * F3 + 64 * h + f]};
#pragma unroll
                for (int m = 0; m < 8; ++m) {
                    float4 gv = *(const float4*)&gbuf[wid + 8 * m][c4];
                    acc2[m] = __builtin_elementwise_fma((v2f){gv.x, gv.y}, wA, acc2[m]);
                    acc2[m] = __builtin_elementwise_fma((v2f){gv.z, gv.w}, wB, acc2[m]);
                }
            }
            {
                float pm0 = -1e30f, pm1 = -1e30f;
#pragma unroll
                for (int m = 0; m < 4; ++m) pm0 = fmaxf(pm0, acc2[m].x + acc2[m].y);
#pragma unroll
                for (int m = 4; m < 8; ++m) pm1 = fmaxf(pm1, acc2[m].x + acc2[m].y);
                pmax[wid][64 * h + f] = pm0;        // group0 partials: rows 0..7
                pmax[8 + wid][64 * h + f] = pm1;    // group1 partials: rows 8..15
            }
        }
        __syncthreads();
        if (tid < 256) {
            int grp = tid >> 7, c = tid & 127;
            float v = pmax[grp * 8][c];
#pragma unroll
            for (int w = 1; w < 8; ++w) v = fmaxf(v, pmax[grp * 8 + w][c]);
            v = fmaxf(v + b2[c], 0.0f);   // relu(max+b) == max(relu(+b))
            out_points[(size_t)(g0 + grp) * F3 + c] = v;
        }
    }
}

extern "C" void kernel_launch(void* const* d_in, const int* in_sizes, int n_in,
                              void* d_out, int out_size, void* d_ws, size_t ws_size,
                              hipStream_t stream) {
    const float* xyz    = (const float*)d_in[0];
    const float* points = (const float*)d_in[1];
    const float* w0 = (const float*)d_in[2];
    const float* b0 = (const float*)d_in[3];
    const float* w1 = (const float*)d_in[4];
    const float* b1 = (const float*)d_in[5];
    const float* w2 = (const float*)d_in[6];
    const float* b2 = (const float*)d_in[7];

    float* out_xyz    = (float*)d_out;
    float* out_points = out_xyz + (size_t)BB * NPOINT * 3;
    int*   ctr        = (int*)d_ws;   // 16 counters, 64B stride

    fused_kernel<<<BB + BB * NPOINT / 2, BLK_T, 0, stream>>>(
        xyz, points, w0, b0, w1, b1, w2, b2, out_xyz, out_points, ctr);
}

// Round 10
// 939.169 us; speedup vs baseline: 1.0236x; 1.0236x over previous
//
#include <hip/hip_runtime.h>
#include <stdint.h>

#define BB 16
#define NN 4096
#define CC 64
#define NPOINT 1024
#define KK 32
#define F1 64
#define F2 64
#define F3 128

#define BLK_T 512          // uniform block size
#define FPS_ACT 256        // active FPS lanes (4 waves)

typedef float v2f __attribute__((ext_vector_type(2)));

// ---------------- DPP 64-lane max-reduce helpers ----------------
#if defined(__has_builtin)
#if __has_builtin(__builtin_amdgcn_update_dpp)
#define HAS_DPP 1
#endif
#endif

#ifdef HAS_DPP
template <int CTRL>
__device__ __forceinline__ unsigned long long dpp_move64(unsigned long long k) {
    int lo = __builtin_amdgcn_update_dpp(0, (int)(unsigned)k,         CTRL, 0xF, 0xF, false);
    int hi = __builtin_amdgcn_update_dpp(0, (int)(unsigned)(k >> 32), CTRL, 0xF, 0xF, false);
    return ((unsigned long long)(unsigned)hi << 32) | (unsigned)lo;
}
__device__ __forceinline__ unsigned long long wave_max_key(unsigned long long key) {
    unsigned long long o;
    o = dpp_move64<0x111>(key); if (o > key) key = o;   // row_shr:1
    o = dpp_move64<0x112>(key); if (o > key) key = o;   // row_shr:2
    o = dpp_move64<0x114>(key); if (o > key) key = o;   // row_shr:4
    o = dpp_move64<0x118>(key); if (o > key) key = o;   // row_shr:8
    o = dpp_move64<0x142>(key); if (o > key) key = o;   // row_bcast15
    o = dpp_move64<0x143>(key); if (o > key) key = o;   // row_bcast31 -> lane63 has max
    return key;
}
#else
__device__ __forceinline__ unsigned long long wave_max_key(unsigned long long key) {
#pragma unroll
    for (int off = 32; off > 0; off >>= 1) {
        unsigned long long o = __shfl_xor(key, off, 64);
        if (o > key) key = o;
    }
    return key;
}
#endif

// shared-memory arena (union of FPS and MLP layouts)
// FPS : xs[4096] ys[4096] zs[4096] @0 (49152) | wred 2x4 u64 @49152 | cbuf 96f @49280
// MLP : gbuf 64x68 @0 (17408) | hbuf 64x64 @17408 (16384) | pmax 16x128 @33792 (8192)
//       cmask 2x64 u64 @41984 (1024) | nbr 2x32 int @43008 (256)  -> 43264
#define SMEM_BYTES 49664   // 3 blocks/CU

__global__ __launch_bounds__(BLK_T)
void fused_kernel(const float* __restrict__ xyz,
                  const float* __restrict__ points,
                  const float* __restrict__ w0, const float* __restrict__ b0,
                  const float* __restrict__ w1, const float* __restrict__ b1,
                  const float* __restrict__ w2, const float* __restrict__ b2,
                  float* __restrict__ out_xyz,
                  float* __restrict__ out_points,
                  int* __restrict__ ctr) {
    __shared__ __align__(16) char smem[SMEM_BYTES];
    const int tid = threadIdx.x;

    if (blockIdx.x < BB) {
        // ================= FPS (blocks 0..15, resident first => no deadlock) ====
        asm volatile("s_setprio 3");
        const int wid8 = tid >> 6;
        if (wid8 >= 4) {
            // barrier-only companion waves: exactly 1 + NPOINT barriers
            for (int i = 0; i < NPOINT + 1; ++i) __syncthreads();
            return;
        }
        float* xs = (float*)smem;
        float* ys = xs + NN;
        float* zs = ys + NN;
        unsigned long long (*wred)[4] =
            (unsigned long long (*)[4])(smem + 49152);
        float* cbuf = (float*)(smem + 49280);   // 32 centroids staging

        const int b = blockIdx.x;
        const int lane = tid & 63, wv = tid >> 6;   // wv 0..3
        const float* __restrict__ xb = xyz + (size_t)b * (NN * 3);

        // pair j holds points p = tid + (2j+h)*256, h = 0/1
        v2f px2[8], py2[8], pz2[8], dd[8];
#pragma unroll
        for (int j = 0; j < 8; ++j) {
#pragma unroll
            for (int h = 0; h < 2; ++h) {
                int p = tid + (2 * j + h) * FPS_ACT;
                float x = xb[p * 3 + 0];
                float y = xb[p * 3 + 1];
                float z = xb[p * 3 + 2];
                px2[j][h] = x; py2[j][h] = y; pz2[j][h] = z;
                xs[p] = x; ys[p] = y; zs[p] = z;
            }
            dd[j] = (v2f){1e10f, 1e10f};
        }
        __syncthreads();

        float cx = xs[0], cy = ys[0], cz = zs[0];
        float* xo = out_xyz + (size_t)b * NPOINT * 3;

        for (int i = 0; i < NPOINT; ++i) {
            if (tid == 0) {
                cbuf[(i & 31) * 3 + 0] = cx;
                cbuf[(i & 31) * 3 + 1] = cy;
                cbuf[(i & 31) * 3 + 2] = cz;
            }
            // ---- packed dist update: v_pk rn-exact, no FMA contraction ----
            {
#pragma clang fp contract(off)
                v2f c2x = (v2f){cx, cx}, c2y = (v2f){cy, cy}, c2z = (v2f){cz, cz};
#pragma unroll
                for (int j = 0; j < 8; ++j) {
                    v2f dx = px2[j] - c2x;
                    v2f dy = py2[j] - c2y;
                    v2f dz = pz2[j] - c2z;
                    v2f ss = (dx * dx + dy * dy) + dz * dz;  // ((x2+y2)+z2), each rn
                    dd[j] = __builtin_elementwise_min(dd[j], ss);
                }
            }
            // ---- lane-local argmax: packed max tree + first-occurrence scan ----
            v2f m0 = __builtin_elementwise_max(dd[0], dd[1]);
            v2f m1 = __builtin_elementwise_max(dd[2], dd[3]);
            v2f m2 = __builtin_elementwise_max(dd[4], dd[5]);
            v2f m3 = __builtin_elementwise_max(dd[6], dd[7]);
            m0 = __builtin_elementwise_max(m0, m1);
            m2 = __builtin_elementwise_max(m2, m3);
            m0 = __builtin_elementwise_max(m0, m2);
            float bd = fmaxf(m0.x, m0.y);
            int bp = 0;
#pragma unroll
            for (int j = 7; j >= 0; --j) {      // descending => smallest p wins
                if (dd[j].y == bd) bp = tid + (2 * j + 1) * FPS_ACT;
                if (dd[j].x == bd) bp = tid + (2 * j + 0) * FPS_ACT;
            }
            unsigned long long key = (((unsigned long long)__float_as_uint(bd)) << 32)
                                   | (unsigned int)(NN - 1 - bp);
            key = wave_max_key(key);
            if (lane == 63) wred[i & 1][wv] = key;
            __syncthreads();

            unsigned long long best = wred[i & 1][0];
#pragma unroll
            for (int w = 1; w < 4; ++w) {
                unsigned long long o = wred[i & 1][w];
                if (o > best) best = o;
            }
            int bi = (NN - 1) - (int)(best & 0xffffffffu);

            // publish 32 centroids every 32 iters
            if (tid == 0 && (i & 31) == 31) {
                const float4* src = (const float4*)cbuf;
                float4* dst = (float4*)(xo + (size_t)(i - 31) * 3);
#pragma unroll
                for (int q = 0; q < 24; ++q) dst[q] = src[q];
                __hip_atomic_store(&ctr[b * 16], i + 1,
                                   __ATOMIC_RELEASE, __HIP_MEMORY_SCOPE_AGENT);
            }
            cx = xs[bi]; cy = ys[bi]; cz = zs[bi];
        }
    } else {
        // ======== fused ball query + gather + MLP + maxpool, 2 groups/block ====
        float (*gbuf)[68] = (float (*)[68])smem;                 // 64 rows
        float (*hbuf)[F1] = (float (*)[F1])(smem + 17408);       // 64 rows
        float (*pmax)[F3] = (float (*)[F3])(smem + 33792);       // 16 rows
        unsigned long long* cmask = (unsigned long long*)(smem + 41984);  // [2][64]
        int* nbr = (int*)(smem + 43008);                          // [2][32]

        const int gi = blockIdx.x - BB;
        const int sp = gi >> 4;         // s-pair, s-major for progressive consume
        const int b = gi & 15;
        const int s0 = sp * 2;
        const int g0 = b * NPOINT + s0;
        const int f = tid & 63;
        const int wid = tid >> 6;       // 0..7

        // wait until centroid s0+1 is published; adaptive backoff (poison<0 => long)
        if (tid == 0) {
            const int target = s0 + 2;
            int c;
            while ((c = __hip_atomic_load(&ctr[b * 16], __ATOMIC_RELAXED,
                                          __HIP_MEMORY_SCOPE_AGENT)) < target) {
                if (target - c > 64) __builtin_amdgcn_s_sleep(64);
                else                 __builtin_amdgcn_s_sleep(4);
            }
            (void)__hip_atomic_load(&ctr[b * 16], __ATOMIC_ACQUIRE,
                                    __HIP_MEMORY_SCOPE_AGENT);
        }
        __syncthreads();

        // centroids via agent-scope loads (LLC-direct, stale-L2-immune).
        // SCALARS ONLY — no local array (dynamic indexing -> scratch, R9 bug).
        unsigned int u;
        u = __hip_atomic_load((unsigned int*)&out_xyz[(size_t)g0 * 3 + 0],
                              __ATOMIC_RELAXED, __HIP_MEMORY_SCOPE_AGENT);
        const float cx0 = __uint_as_float(u);
        u = __hip_atomic_load((unsigned int*)&out_xyz[(size_t)g0 * 3 + 1],
                              __ATOMIC_RELAXED, __HIP_MEMORY_SCOPE_AGENT);
        const float cy0 = __uint_as_float(u);
        u = __hip_atomic_load((unsigned int*)&out_xyz[(size_t)g0 * 3 + 2],
                              __ATOMIC_RELAXED, __HIP_MEMORY_SCOPE_AGENT);
        const float cz0 = __uint_as_float(u);
        u = __hip_atomic_load((unsigned int*)&out_xyz[(size_t)(g0 + 1) * 3 + 0],
                              __ATOMIC_RELAXED, __HIP_MEMORY_SCOPE_AGENT);
        const float cx1 = __uint_as_float(u);
        u = __hip_atomic_load((unsigned int*)&out_xyz[(size_t)(g0 + 1) * 3 + 1],
                              __ATOMIC_RELAXED, __HIP_MEMORY_SCOPE_AGENT);
        const float cy1 = __uint_as_float(u);
        u = __hip_atomic_load((unsigned int*)&out_xyz[(size_t)(g0 + 1) * 3 + 2],
                              __ATOMIC_RELAXED, __HIP_MEMORY_SCOPE_AGENT);
        const float cz1 = __uint_as_float(u);

        // ---- phase A1: 8 waves scan all 4096 points, 2 centroids at once ----
        {
            const float* __restrict__ xb = xyz + (size_t)b * (NN * 3);
#pragma unroll
            for (int j = 0; j < 8; ++j) {
                int chunk = wid * 8 + j;
                int p = chunk * 64 + f;
                float x = xb[p * 3 + 0];
                float y = xb[p * 3 + 1];
                float z = xb[p * 3 + 2];
                float dx0 = __fsub_rn(cx0, x), dy0 = __fsub_rn(cy0, y), dz0 = __fsub_rn(cz0, z);
                float d20 = __fadd_rn(__fadd_rn(__fmul_rn(dx0, dx0), __fmul_rn(dy0, dy0)),
                                      __fmul_rn(dz0, dz0));
                float dx1 = __fsub_rn(cx1, x), dy1 = __fsub_rn(cy1, y), dz1 = __fsub_rn(cz1, z);
                float d21 = __fadd_rn(__fadd_rn(__fmul_rn(dx1, dx1), __fmul_rn(dy1, dy1)),
                                      __fmul_rn(dz1, dz1));
                unsigned long long m0 = __ballot(d20 <= 0.04f);
                unsigned long long m1 = __ballot(d21 <= 0.04f);
                if (f == 0) { cmask[chunk] = m0; cmask[64 + chunk] = m1; }
            }
        }
        __syncthreads();

        // ---- phase A2: waves 0,1 — ordered compaction per group ----
        if (tid < 128) {
            const int grp = wid;
            unsigned long long m = cmask[grp * 64 + f];
            int cnt = (int)__popcll(m);
            int v = cnt;
#pragma unroll
            for (int off = 1; off < 64; off <<= 1) {
                int u2 = __shfl_up(v, off, 64);
                if (f >= off) v += u2;
            }
            int excl = v - cnt;
            int total = __shfl(v, 63, 64);
            unsigned long long mm = m;
            int r = excl;
            while (mm && r < KK) {
                int bpos = __ffsll(mm) - 1;
                mm &= mm - 1;
                nbr[grp * 32 + (r++)] = f * 64 + bpos;
            }
            if (total < KK) {
                unsigned long long nz = __ballot(cnt > 0);
                int fchunk = __ffsll(nz) - 1;
                unsigned long long fm = cmask[grp * 64 + fchunk];
                int first = fchunk * 64 + __ffsll(fm) - 1;
                if (f >= total && f < KK) nbr[grp * 32 + f] = first;
            }
        }
        __syncthreads();

        // ---- phase B: gather both groups into LDS (rows 0..31 g0, 32..63 g1) ----
        {
            const float* __restrict__ pb = points + (size_t)b * NN * CC;
#pragma unroll
            for (int m = 0; m < 8; ++m) {
                int r = wid + 8 * m;           // 0..63
                int grp = r >> 5, k = r & 31;
                int idx = nbr[grp * 32 + k] & (NN - 1);
                gbuf[r][f] = pb[(size_t)idx * CC + f];
            }
            if (tid < 192) {
                int r = tid & 63, q = tid >> 6;
                int grp = r >> 5, k = r & 31;
                int idx = nbr[grp * 32 + k] & (NN - 1);
                float v = xyz[((size_t)b * NN + idx) * 3 + q];
                // pure register selects (v_cndmask) — NO local array
                float c0 = (q == 0) ? cx0 : ((q == 1) ? cy0 : cz0);
                float c1 = (q == 0) ? cx1 : ((q == 1) ? cy1 : cz1);
                float cq = grp ? c1 : c0;
                gbuf[r][CC + q] = __fsub_rn(v, cq);
            }
        }
        __syncthreads();

        v2f acc2[8];

        // ---- layer 1: 67 -> 64 ----
#pragma unroll
        for (int m = 0; m < 8; ++m) acc2[m] = (v2f){0.0f, 0.0f};
#pragma unroll 4
        for (int c4 = 0; c4 < 64; c4 += 4) {
            v2f wA = (v2f){w0[(c4 + 0) * F1 + f], w0[(c4 + 1) * F1 + f]};
            v2f wB = (v2f){w0[(c4 + 2) * F1 + f], w0[(c4 + 3) * F1 + f]};
#pragma unroll
            for (int m = 0; m < 8; ++m) {
                float4 gv = *(const float4*)&gbuf[wid + 8 * m][c4];
                acc2[m] = __builtin_elementwise_fma((v2f){gv.x, gv.y}, wA, acc2[m]);
                acc2[m] = __builtin_elementwise_fma((v2f){gv.z, gv.w}, wB, acc2[m]);
            }
        }
        {
            float wv0 = w0[64 * F1 + f];
            float wv1 = w0[65 * F1 + f];
            float wv2 = w0[66 * F1 + f];
            float bb = b0[f];
#pragma unroll
            for (int m = 0; m < 8; ++m) {
                int r = wid + 8 * m;
                float a = acc2[m].x + acc2[m].y;
                a = fmaf(gbuf[r][64], wv0, a);
                a = fmaf(gbuf[r][65], wv1, a);
                a = fmaf(gbuf[r][66], wv2, a);
                hbuf[r][f] = fmaxf(a + bb, 0.0f);
            }
        }
        __syncthreads();

        // ---- layer 2: 64 -> 64 ----
#pragma unroll
        for (int m = 0; m < 8; ++m) acc2[m] = (v2f){0.0f, 0.0f};
#pragma unroll 4
        for (int c4 = 0; c4 < 64; c4 += 4) {
            v2f wA = (v2f){w1[(c4 + 0) * F2 + f], w1[(c4 + 1) * F2 + f]};
            v2f wB = (v2f){w1[(c4 + 2) * F2 + f], w1[(c4 + 3) * F2 + f]};
#pragma unroll
            for (int m = 0; m < 8; ++m) {
                float4 gv = *(const float4*)&hbuf[wid + 8 * m][c4];
                acc2[m] = __builtin_elementwise_fma((v2f){gv.x, gv.y}, wA, acc2[m]);
                acc2[m] = __builtin_elementwise_fma((v2f){gv.z, gv.w}, wB, acc2[m]);
            }
        }
        {
            float bb = b1[f];
#pragma unroll
            for (int m = 0; m < 8; ++m)
                gbuf[wid + 8 * m][f] = fmaxf(acc2[m].x + acc2[m].y + bb, 0.0f);
        }
        __syncthreads();

        // ---- layer 3: 64 -> 128 in two output-column halves + maxpool ----
        // rows m 0..3 -> group0 ; m 4..7 -> group1
#pragma unroll
        for (int h = 0; h < 2; ++h) {
#pragma unroll
            for (int m = 0; m < 8; ++m) acc2[m] = (v2f){0.0f, 0.0f};
#pragma unroll 4
            for (int c4 = 0; c4 < 64; c4 += 4) {
                v2f wA = (v2f){w2[(c4 + 0) * F3 + 64 * h + f], w2[(c4 + 1) * F3 + 64 * h + f]};
                v2f wB = (v2f){w2[(c4 + 2) * F3 + 64 * h + f], w2[(c4 + 3) * F3 + 64 * h + f]};
#pragma unroll
                for (int m = 0; m < 8; ++m) {
                    float4 gv = *(const float4*)&gbuf[wid + 8 * m][c4];
                    acc2[m] = __builtin_elementwise_fma((v2f){gv.x, gv.y}, wA, acc2[m]);
                    acc2[m] = __builtin_elementwise_fma((v2f){gv.z, gv.w}, wB, acc2[m]);
                }
            }
            {
                float pm0 = -1e30f, pm1 = -1e30f;
#pragma unroll
                for (int m = 0; m < 4; ++m) pm0 = fmaxf(pm0, acc2[m].x + acc2[m].y);
#pragma unroll
                for (int m = 4; m < 8; ++m) pm1 = fmaxf(pm1, acc2[m].x + acc2[m].y);
                pmax[wid][64 * h + f] = pm0;        // group0 partials: rows 0..7
                pmax[8 + wid][64 * h + f] = pm1;    // group1 partials: rows 8..15
            }
        }
        __syncthreads();
        if (tid < 256) {
            int grp = tid >> 7, c = tid & 127;
            float v = pmax[grp * 8][c];
#pragma unroll
            for (int w = 1; w < 8; ++w) v = fmaxf(v, pmax[grp * 8 + w][c]);
            v = fmaxf(v + b2[c], 0.0f);   // relu(max+b) == max(relu(+b))
            out_points[(size_t)(g0 + grp) * F3 + c] = v;
        }
    }
}

extern "C" void kernel_launch(void* const* d_in, const int* in_sizes, int n_in,
                              void* d_out, int out_size, void* d_ws, size_t ws_size,
                              hipStream_t stream) {
    const float* xyz    = (const float*)d_in[0];
    const float* points = (const float*)d_in[1];
    const float* w0 = (const float*)d_in[2];
    const float* b0 = (const float*)d_in[3];
    const float* w1 = (const float*)d_in[4];
    const float* b1 = (const float*)d_in[5];
    const float* w2 = (const float*)d_in[6];
    const float* b2 = (const float*)d_in[7];

    float* out_xyz    = (float*)d_out;
    float* out_points = out_xyz + (size_t)BB * NPOINT * 3;
    int*   ctr        = (int*)d_ws;   // 16 counters, 64B stride

    fused_kernel<<<BB + BB * NPOINT / 2, BLK_T, 0, stream>>>(
        xyz, points, w0, b0, w1, b1, w2, b2, out_xyz, out_points, ctr);
}